// Round 3
// baseline (321.270 us; speedup 1.0000x reference)
//
#include <hip/hip_runtime.h>

// Problem constants (reference: M, B, D = 32, 64, 8192)
#define Mh 32
#define Bh 64
#define Dh 8192
#define STG 128            // k per LDS stage in gram (512 B per row per stage)

typedef unsigned int u32;

// async global->LDS DMA, 16 B per lane; LDS dest = uniform base + lane*16
__device__ __forceinline__ void async_cp16(const float* g, float* l) {
    __builtin_amdgcn_global_load_lds((const __attribute__((address_space(1))) u32*)g,
                                     (__attribute__((address_space(3))) u32*)l, 16, 0, 0);
}

// ---------------------------------------------------------------------------
// Kernel A: batched Gram partials. grid = 64 b x nch k-chunks, 256 threads.
// Double-buffered LDS via global_load_lds (no staging VGPRs -> no spills).
// XOR swizzle applied on the GLOBAL side (lane->col permutation) so the
// fixed lane-order LDS layout lands swizzled; compute reads conflict-free.
// ---------------------------------------------------------------------------
__global__ __launch_bounds__(256) void gram_kernel(
    const float* __restrict__ s, const float* __restrict__ y,
    const float* __restrict__ frc, float* __restrict__ ws,
    int nch, int kch,
    long off_psy, long off_pyy, long off_pvs, long off_pvy)
{
    __shared__ float sT[2][32 * STG];   // 16 KB x2
    __shared__ float yT[2][32 * STG];   // 16 KB x2  -> 64 KB total (max)
    const int b  = blockIdx.x & 63;
    const int ch = blockIdx.x >> 6;
    const int k0 = ch * kch;
    const int nst = kch / STG;
    const int t  = threadIdx.x;
    const int w  = t >> 6;
    const int l  = t & 63;
    const int tx = l & 7;
    const int ty = l >> 3;

    // staging: wave w owns instrs j=4w..4w+3; instr j covers rows 2j,2j+1.
    // lane l: row = 2j + (l>>5), LDS f4-slot cs = l&31, global col = cs ^ swz,
    // swz = (j>>1)&7 == (row>>2)&7 (consistent with compute-side swizzle).
    const float* sp[4]; const float* yp[4]; int lofs[4];
    #pragma unroll
    for (int jj = 0; jj < 4; ++jj) {
        const int j   = (w << 2) + jj;
        const int row = (j << 1) + (l >> 5);
        const int cg  = (l & 31) ^ ((j >> 1) & 7);
        const size_t goff = ((size_t)row * Bh + b) * Dh + k0 + (cg << 2);
        sp[jj] = s + goff;
        yp[jj] = y + goff;
        lofs[jj] = j << 8;             // j*256 floats = 2 rows * STG
    }
    const float* frcp = frc + (size_t)b * Dh + k0;

    float acc_sy[4][4] = {};
    float acc_yy[4][4] = {};
    float avs[4] = {}, avy[4] = {};

    // prologue: stage 0 into buffer 0
    #pragma unroll
    for (int jj = 0; jj < 4; ++jj) {
        async_cp16(sp[jj], &sT[0][lofs[jj]]);
        async_cp16(yp[jj], &yT[0][lofs[jj]]);
        sp[jj] += STG; yp[jj] += STG;
    }

    for (int st = 0; st < nst; ++st) {
        const int cur = st & 1;
        __syncthreads();   // drains this stage's DMA; guards buffer reuse

        // frc values for THIS stage (wave-uniform addresses), issued BEFORE
        // next stage's DMA so the fv-wait doesn't drain the DMA queue.
        float4 fvs[8];
        #pragma unroll
        for (int kk = 0; kk < 8; ++kk)
            fvs[kk] = *(const float4*)(frcp + (((w << 3) + kk) << 2));
        __builtin_amdgcn_sched_barrier(0);
        frcp += STG;

        if (st + 1 < nst) {
            #pragma unroll
            for (int jj = 0; jj < 4; ++jj) {
                async_cp16(sp[jj], &sT[cur ^ 1][lofs[jj]]);
                async_cp16(yp[jj], &yT[cur ^ 1][lofs[jj]]);
                sp[jj] += STG; yp[jj] += STG;
            }
        }

        const float* sb = sT[cur];
        const float* yb = yT[cur];
        #pragma unroll
        for (int kk = 0; kk < 8; ++kk) {
            const int c0 = (w << 3) + kk;
            float4 sv[4], tv[4], xv[4];
            #pragma unroll
            for (int aa = 0; aa < 4; ++aa) {
                sv[aa] = *(const float4*)&sb[((ty << 2) + aa) * STG + ((c0 ^ ty) << 2)];
                tv[aa] = *(const float4*)&yb[((ty << 2) + aa) * STG + ((c0 ^ ty) << 2)];
                xv[aa] = *(const float4*)&yb[((tx << 2) + aa) * STG + ((c0 ^ tx) << 2)];
            }
            const float4 fv = fvs[kk];
            #pragma unroll
            for (int aa = 0; aa < 4; ++aa) {
                #pragma unroll
                for (int cc = 0; cc < 4; ++cc) {
                    acc_sy[aa][cc] += sv[aa].x * xv[cc].x + sv[aa].y * xv[cc].y
                                    + sv[aa].z * xv[cc].z + sv[aa].w * xv[cc].w;
                    acc_yy[aa][cc] += tv[aa].x * xv[cc].x + tv[aa].y * xv[cc].y
                                    + tv[aa].z * xv[cc].z + tv[aa].w * xv[cc].w;
                }
                avs[aa] += sv[aa].x * fv.x + sv[aa].y * fv.y + sv[aa].z * fv.z + sv[aa].w * fv.w;
                avy[aa] += tv[aa].x * fv.x + tv[aa].y * fv.y + tv[aa].z * fv.z + tv[aa].w * fv.w;
            }
        }
    }

    // cross-wave reduction: reuse sT[0] (SY), sT[1] (YY), yT[0] (vs/vy)
    __syncthreads();
    float* SY = &sT[0][0];
    float* YY = &sT[1][0];
    float* VV = &yT[0][0];
    for (int wv = 0; wv < 4; ++wv) {
        if (w == wv) {
            #pragma unroll
            for (int aa = 0; aa < 4; ++aa) {
                #pragma unroll
                for (int cc = 0; cc < 4; ++cc) {
                    const int e = ((ty << 2) + aa) * 32 + (tx << 2) + cc;
                    if (wv == 0) { SY[e] = acc_sy[aa][cc];  YY[e] = acc_yy[aa][cc]; }
                    else         { SY[e] += acc_sy[aa][cc]; YY[e] += acc_yy[aa][cc]; }
                }
                if (tx == 0) {
                    const int i = (ty << 2) + aa;
                    if (wv == 0) { VV[i] = avs[aa];  VV[32 + i] = avy[aa]; }
                    else         { VV[i] += avs[aa]; VV[32 + i] += avy[aa]; }
                }
            }
        }
        __syncthreads();
    }

    float* PSY = ws + off_psy + ((size_t)ch * Bh + b) * 1024;
    float* PYY = ws + off_pyy + ((size_t)ch * Bh + b) * 1024;
    *(float4*)&PSY[t << 2] = *(const float4*)&SY[t << 2];
    *(float4*)&PYY[t << 2] = *(const float4*)&YY[t << 2];
    if (t < 32)      ws[off_pvs + (ch * 64 + b) * 32 + t] = VV[t];
    else if (t < 64) ws[off_pvy + (ch * 64 + b) * 32 + (t - 32)] = VV[t];
}

// ---------------------------------------------------------------------------
// Kernel B: reduce nch partials, then the M=32 f64 recursion. 1 block per b.
// ---------------------------------------------------------------------------
__global__ __launch_bounds__(256) void recur_kernel(
    float* __restrict__ ws, int nch,
    long off_psy, long off_pyy, long off_pvs, long off_pvy,
    long off_cy, long off_cs, long off_g)
{
    __shared__ float WSY[1024], WYY[1024], VS[32], VY[32];
    const int b = blockIdx.x;
    const int t = threadIdx.x;

    float4 a4 = make_float4(0.f, 0.f, 0.f, 0.f);
    float4 c4 = make_float4(0.f, 0.f, 0.f, 0.f);
    for (int ch = 0; ch < nch; ++ch) {
        const float4 u = *(const float4*)&ws[off_psy + ((size_t)ch * Bh + b) * 1024 + (t << 2)];
        const float4 v = *(const float4*)&ws[off_pyy + ((size_t)ch * Bh + b) * 1024 + (t << 2)];
        a4.x += u.x; a4.y += u.y; a4.z += u.z; a4.w += u.w;
        c4.x += v.x; c4.y += v.y; c4.z += v.z; c4.w += v.w;
    }
    *(float4*)&WSY[t << 2] = a4;
    *(float4*)&WYY[t << 2] = c4;
    if (t < 32) {
        float av = 0.f, cv = 0.f;
        for (int ch = 0; ch < nch; ++ch) {
            av += ws[off_pvs + (ch * 64 + b) * 32 + t];
            cv += ws[off_pvy + (ch * 64 + b) * 32 + t];
        }
        VS[t] = av; VY[t] = cv;
    }
    __syncthreads();
    if (t >= 64) return;

    const int i = t & 31;
    float row_sy[32], col_sy[32], row_yy[32];
    #pragma unroll
    for (int j = 0; j < 32; ++j) {
        row_sy[j] = WSY[i * 32 + j];
        col_sy[j] = WSY[j * 32 + i];
        row_yy[j] = WYY[i * 32 + j];
    }

    const double r = 1.0 / (double)row_sy[i];
    double acc = -(double)VS[i];
    double a_val = 0.0;
    #pragma unroll
    for (int j = 31; j >= 0; --j) {
        const double aj = __shfl(r, j) * __shfl(acc, j);
        if (i == j) a_val = aj;
        if (i < j)  acc -= aj * (double)row_sy[j];
    }

    const double g = (double)WSY[31 * 32 + 31] / (double)WYY[31 * 32 + 31];

    double u = -(double)VY[i];
    #pragma unroll
    for (int j = 0; j < 32; ++j)
        u -= __shfl(a_val, j) * (double)row_yy[j];
    u *= g;

    double tt = u;
    double b_val = 0.0;
    #pragma unroll
    for (int j = 0; j < 32; ++j) {
        const double bj = __shfl(r, j) * __shfl(tt, j);
        if (i == j) b_val = bj;
        const double dj = __shfl(a_val, j) - bj;
        if (i > j) tt += dj * (double)col_sy[j];
    }

    if (t < 32) {
        ws[off_cy + b * 32 + i] = (float)(g * a_val);
        ws[off_cs + b * 32 + i] = (float)(b_val - a_val);
    }
    if (t == 0) ws[off_g + b] = (float)g;
}

// ---------------------------------------------------------------------------
// Kernel C1 (two-pass path): pure streaming. block (i,b) reads s/y rows
// contiguously (32 KB each) and writes cy*y+cs*s to part[b][i][:] (32 KB).
// Pattern-identical to a copy kernel -> should run at HBM ceiling.
// ---------------------------------------------------------------------------
__global__ __launch_bounds__(256) void wrow_kernel(
    const float* __restrict__ s, const float* __restrict__ y,
    const float* __restrict__ ws, float* __restrict__ part_ws,
    long off_cy, long off_cs, long off_part)
{
    const int b = blockIdx.x & 63;
    const int i = blockIdx.x >> 6;        // grid 2048: consecutive blocks = consecutive memory
    const int t = threadIdx.x;
    const float a1 = ws[off_cy + (b << 5) + i];
    const float a2 = ws[off_cs + (b << 5) + i];
    const float* ys = y + ((size_t)i * Bh + b) * Dh;
    const float* ss = s + ((size_t)i * Bh + b) * Dh;
    float* pd = part_ws + off_part + ((size_t)b * Mh + i) * Dh;
    #pragma unroll
    for (int rep = 0; rep < 8; ++rep) {
        const int d = (rep << 10) + (t << 2);
        const float4 yv = *(const float4*)(ys + d);
        const float4 sv = *(const float4*)(ss + d);
        float4 o;
        o.x = a1 * yv.x + a2 * sv.x;
        o.y = a1 * yv.y + a2 * sv.y;
        o.z = a1 * yv.z + a2 * sv.z;
        o.w = a1 * yv.w + a2 * sv.w;
        *(float4*)(pd + d) = o;
    }
}

// ---------------------------------------------------------------------------
// Kernel C2 (two-pass path): out[b][d] = g*frc + sum_i part[b][i][d].
// 32 streams at 32 KB stride inside a 1 MB window (vs 2 MB stride before).
// ---------------------------------------------------------------------------
__global__ __launch_bounds__(256) void finish_kernel(
    const float* __restrict__ frc, const float* __restrict__ ws,
    float* __restrict__ out, long off_g, long off_part)
{
    const int b  = blockIdx.x & 63;
    const int ch = blockIdx.x >> 6;       // grid 512 (8 chunks)
    const int t  = threadIdx.x;
    const int d  = (ch << 10) + (t << 2);
    const float g = ws[off_g + b];
    const float4 fv = *(const float4*)(frc + (size_t)b * Dh + d);
    float4 acc;
    acc.x = g * fv.x; acc.y = g * fv.y; acc.z = g * fv.z; acc.w = g * fv.w;
    const float* p = ws + off_part + ((size_t)b * Mh) * Dh + d;
    #pragma unroll
    for (int grp = 0; grp < 4; ++grp) {
        float4 v[8];
        #pragma unroll
        for (int j = 0; j < 8; ++j)
            v[j] = *(const float4*)(p + (size_t)(grp * 8 + j) * Dh);
        #pragma unroll
        for (int j = 0; j < 8; ++j) {
            acc.x += v[j].x; acc.y += v[j].y; acc.z += v[j].z; acc.w += v[j].w;
        }
    }
    *(float4*)(out + (size_t)b * Dh + d) = acc;
}

// ---------------------------------------------------------------------------
// Kernel C (fallback single-pass, small ws): R2 combine, verified correct.
// ---------------------------------------------------------------------------
__global__ __launch_bounds__(256) void combine_kernel(
    const float* __restrict__ s, const float* __restrict__ y,
    const float* __restrict__ frc, const float* __restrict__ ws,
    float* __restrict__ out, long off_cy, long off_cs, long off_g)
{
    __shared__ float cy[32], cs[32];
    const int b  = blockIdx.x & 63;
    const int ch = blockIdx.x >> 6;
    const int t  = threadIdx.x;
    if (t < 32) { cy[t] = ws[off_cy + b * 32 + t]; cs[t] = ws[off_cs + b * 32 + t]; }
    __syncthreads();

    const int d = ch * 1024 + (t << 2);
    const size_t base = (size_t)b * Dh + d;
    const float g = ws[off_g + b];
    const float4 fv = *(const float4*)(frc + base);
    float4 acc;
    acc.x = g * fv.x; acc.y = g * fv.y; acc.z = g * fv.z; acc.w = g * fv.w;

    const float* py = y + base;
    const float* ps = s + base;
    #pragma unroll
    for (int grp = 0; grp < 4; ++grp) {
        float4 yv[8], sv[8];
        #pragma unroll
        for (int j = 0; j < 8; ++j) {
            const size_t off = (size_t)(grp * 8 + j) * ((size_t)Bh * Dh);
            yv[j] = *(const float4*)(py + off);
            sv[j] = *(const float4*)(ps + off);
        }
        #pragma unroll
        for (int j = 0; j < 8; ++j) {
            const float a1 = cy[grp * 8 + j], a2 = cs[grp * 8 + j];
            acc.x += a1 * yv[j].x + a2 * sv[j].x;
            acc.y += a1 * yv[j].y + a2 * sv[j].y;
            acc.z += a1 * yv[j].z + a2 * sv[j].z;
            acc.w += a1 * yv[j].w + a2 * sv[j].w;
        }
    }
    *(float4*)(out + base) = acc;
}

extern "C" void kernel_launch(void* const* d_in, const int* in_sizes, int n_in,
                              void* d_out, int out_size, void* d_ws, size_t ws_size,
                              hipStream_t stream)
{
    const float* s   = (const float*)d_in[0];
    const float* y   = (const float*)d_in[1];
    const float* frc = (const float*)d_in[2];
    float* out = (float*)d_out;
    float* ws  = (float*)d_ws;

    const long floats = (long)(ws_size / 4);

    // layout for nch=16 (preferred) or nch=8 (compact fallback)
    int nch = 16;
    long P, off_psy, off_pyy, off_pvs, off_pvy, off_cy, off_cs, off_g, endc;
    for (int attempt = 0; attempt < 2; ++attempt) {
        P = (long)nch * 64 * 1024;
        off_psy = 0; off_pyy = P; off_pvs = 2 * P;
        off_pvy = off_pvs + (long)nch * 64 * 32;
        off_cy  = off_pvy + (long)nch * 64 * 32;
        off_cs  = off_cy + 2048;
        off_g   = off_cs + 2048;
        endc    = off_g + 64;
        if (endc <= floats || nch == 8) break;
        nch = 8;
    }
    const long off_part = (endc + 3) & ~3L;
    const bool two_pass = (off_part + (long)Bh * Mh * Dh) <= floats;
    const int kch = Dh / nch;

    gram_kernel<<<dim3(Bh * nch), dim3(256), 0, stream>>>(
        s, y, frc, ws, nch, kch, off_psy, off_pyy, off_pvs, off_pvy);
    recur_kernel<<<dim3(Bh), dim3(256), 0, stream>>>(
        ws, nch, off_psy, off_pyy, off_pvs, off_pvy, off_cy, off_cs, off_g);
    if (two_pass) {
        wrow_kernel<<<dim3(Bh * Mh), dim3(256), 0, stream>>>(
            s, y, ws, ws, off_cy, off_cs, off_part);
        finish_kernel<<<dim3(Bh * 8), dim3(256), 0, stream>>>(
            frc, ws, out, off_g, off_part);
    } else {
        combine_kernel<<<dim3(Bh * 8), dim3(256), 0, stream>>>(
            s, y, frc, ws, out, off_cy, off_cs, off_g);
    }
}